// Round 15
// baseline (213.476 us; speedup 1.0000x reference)
//
#include <hip/hip_runtime.h>
#include <hip/hip_fp16.h>
#include <math.h>
#include <stdint.h>

// MSDeformAttn. N=2, C=256, M=8, L=4, P=4, D=32, LEN=21760
// R15: R12 state + gather j-parity split across thread pairs (8 iters/thread,
//      2x wave count, shfl_xor(4) combine). Levels stay compile-time (l=jj>>1).

constexpr int NB  = 2;
constexpr int C   = 256;
constexpr int M   = 8;
constexpr int D   = 32;
constexpr int LEN = 21760;
constexpr int QCHc = LEN / 2;   // 10880 queries per chunk (per batch)

typedef __attribute__((ext_vector_type(8))) short short8v;
typedef __attribute__((ext_vector_type(4))) float f32x4;

__device__ __forceinline__ short f2bf(float x) {
  uint32_t u = __float_as_uint(x);
  u = (u + 0x7fffu + ((u >> 16) & 1u)) >> 16;
  return (short)u;
}

// ---------------------------------------------------------------------------
// Weight prepack into per-fragment-coalesced layout:
// WP[((ks*NCG+cg)*64 + lane)*8 + e] = W[ks*32 + (lane>>4)*8 + e][cg*16 + (lane&15)]
// ---------------------------------------------------------------------------
__global__ __launch_bounds__(256) void k_wpack(
    const float* __restrict__ Wval, const float* __restrict__ Woff,
    const float* __restrict__ Wattn, const float* __restrict__ Wout,
    short* __restrict__ WvP, short* __restrict__ WdP, short* __restrict__ WoP) {
  const int job = blockIdx.y;
  const int ncols = (job == 1) ? 384 : 256;
  const int NCG = ncols / 16;
  const int elems = 256 * ncols;
  const int idx = blockIdx.x * 256 + threadIdx.x;
  if (idx >= elems) return;
  const int e    = idx & 7;
  const int lane = (idx >> 3) & 63;
  const int lr = lane & 15, lk = lane >> 4;
  const int cgks = idx >> 9;
  const int cg = cgks % NCG, ks = cgks / NCG;
  const int k = ks * 32 + lk * 8 + e;
  const int col = cg * 16 + lr;
  float v;
  if (job == 0)      v = Wval[(size_t)k * 256 + col];
  else if (job == 2) v = Wout[(size_t)k * 256 + col];
  else               v = (col < 256) ? Woff[(size_t)k * 256 + col]
                                     : Wattn[(size_t)k * 128 + col - 256];
  short* dst = (job == 0) ? WvP : (job == 1) ? WdP : WoP;
  dst[idx] = f2bf(v);
}

__device__ __forceinline__ short8v ldBP(const short* __restrict__ WP, int NCG,
                                        int cg, int ks, int lane) {
  const int4 v = *(const int4*)(WP + ((size_t)((ks * NCG + cg) * 64 + lane)) * 8);
  union { int4 i; short8v s; } u; u.i = v; return u.s;
}

// ---------------------------------------------------------------------------
// LDS staging (32 rows x 256 k, bf16, XOR-swizzled) + A fragment loads
// ---------------------------------------------------------------------------
__device__ __forceinline__ void stage_cast(const float* __restrict__ p, char* sm, int t) {
  const int r = t >> 3, seg = t & 7;
  const float4* s = (const float4*)(p + (size_t)r * C + seg * 32);
  short v[32];
#pragma unroll
  for (int i = 0; i < 8; ++i) {
    float4 f = s[i];
    v[i * 4 + 0] = f2bf(f.x); v[i * 4 + 1] = f2bf(f.y);
    v[i * 4 + 2] = f2bf(f.z); v[i * 4 + 3] = f2bf(f.w);
  }
#pragma unroll
  for (int i = 0; i < 4; ++i) {
    const int kb = (seg * 32 + i * 8) * 2;
    *(int4*)(sm + r * 512 + (kb ^ ((r & 7) << 4))) = ((const int4*)v)[i];
  }
}

__device__ __forceinline__ void stage_bf16(const short* __restrict__ p, char* sm, int t) {
  const int r = t >> 3, seg = t & 7;
  const int4* s = (const int4*)(p + (size_t)r * C + seg * 32);
#pragma unroll
  for (int i = 0; i < 4; ++i) {
    const int kb = (seg * 32 + i * 8) * 2;
    *(int4*)(sm + r * 512 + (kb ^ ((r & 7) << 4))) = s[i];
  }
}

__device__ __forceinline__ short8v ldsA(const char* sm, int lane, int rt, int ks) {
  const int row = rt * 16 + (lane & 15);
  const int kb  = ks * 64 + ((lane >> 4) << 4);
  const int4 v = *(const int4*)(sm + row * 512 + (kb ^ ((row & 7) << 4)));
  union { int4 i; short8v s; } u; u.i = v; return u.s;
}

#define MFMA __builtin_amdgcn_mfma_f32_16x16x32_bf16

// ---------------------------------------------------------------------------
// GEMM body shared by valproj/outproj (proven in R10)
// ---------------------------------------------------------------------------
#define GEMM_BODY(WP)                                                       \
  short8v a[2][8];                                                          \
  _Pragma("unroll") for (int rt = 0; rt < 2; ++rt)                          \
  _Pragma("unroll") for (int ks = 0; ks < 8; ++ks)                          \
      a[rt][ks] = ldsA(smA, lane, rt, ks);                                  \
  f32x4 acc[2][4];                                                          \
  _Pragma("unroll") for (int rt = 0; rt < 2; ++rt)                          \
  _Pragma("unroll") for (int ct = 0; ct < 4; ++ct)                          \
      acc[rt][ct] = (f32x4){0.f, 0.f, 0.f, 0.f};                            \
  short8v b0[8], b1[8];                                                     \
  _Pragma("unroll") for (int ks = 0; ks < 8; ++ks)                          \
      b0[ks] = ldBP(WP, 16, cg0 + 0, ks, lane);                             \
  _Pragma("unroll") for (int ks = 0; ks < 8; ++ks)                          \
      b1[ks] = ldBP(WP, 16, cg0 + 1, ks, lane);                             \
  _Pragma("unroll") for (int ks = 0; ks < 8; ++ks) {                        \
    acc[0][0] = MFMA(a[0][ks], b0[ks], acc[0][0], 0, 0, 0);                 \
    acc[1][0] = MFMA(a[1][ks], b0[ks], acc[1][0], 0, 0, 0);                 \
  }                                                                         \
  _Pragma("unroll") for (int ks = 0; ks < 8; ++ks)                          \
      b0[ks] = ldBP(WP, 16, cg0 + 2, ks, lane);                             \
  _Pragma("unroll") for (int ks = 0; ks < 8; ++ks) {                        \
    acc[0][1] = MFMA(a[0][ks], b1[ks], acc[0][1], 0, 0, 0);                 \
    acc[1][1] = MFMA(a[1][ks], b1[ks], acc[1][1], 0, 0, 0);                 \
  }                                                                         \
  _Pragma("unroll") for (int ks = 0; ks < 8; ++ks)                          \
      b1[ks] = ldBP(WP, 16, cg0 + 3, ks, lane);                             \
  _Pragma("unroll") for (int ks = 0; ks < 8; ++ks) {                        \
    acc[0][2] = MFMA(a[0][ks], b0[ks], acc[0][2], 0, 0, 0);                 \
    acc[1][2] = MFMA(a[1][ks], b0[ks], acc[1][2], 0, 0, 0);                 \
  }                                                                         \
  _Pragma("unroll") for (int ks = 0; ks < 8; ++ks) {                        \
    acc[0][3] = MFMA(a[0][ks], b1[ks], acc[0][3], 0, 0, 0);                 \
    acc[1][3] = MFMA(a[1][ks], b1[ks], acc[1][3], 0, 0, 0);                 \
  }

// ---------------------------------------------------------------------------
// Kernel: value = bf16mm(input_flatten, WvP) + bv -> fp16 value[n][m][pix][d]
// ---------------------------------------------------------------------------
__global__ __launch_bounds__(256, 2) void k_valproj(
    const float* __restrict__ infl, const short* __restrict__ WvP,
    const float* __restrict__ bv, __half* __restrict__ value) {
  __shared__ __align__(16) char smA[16384];
  const int t = threadIdx.x, lane = t & 63, w = t >> 6;
  const int r0 = blockIdx.x * 32;
  stage_cast(infl + (size_t)r0 * C, smA, t);
  __syncthreads();
  const int cg0 = w * 4;
  const int lr = lane & 15, lk = lane >> 4;
  GEMM_BODY(WvP)

  const int n = (blockIdx.x >= (LEN / 32)) ? 1 : 0;
  const int pixbase = r0 - n * LEN;
#pragma unroll
  for (int ct = 0; ct < 4; ++ct) {
    const int col = (cg0 + ct) * 16 + lr;
    const float bb = bv[col];
    const int m = col >> 5, d = col & 31;
    __half* vp = value + ((size_t)(n * 8 + m) * LEN) * 32 + d;
#pragma unroll
    for (int rt = 0; rt < 2; ++rt)
#pragma unroll
      for (int r = 0; r < 4; ++r) {
        const int pix = pixbase + rt * 16 + lk * 4 + r;
        vp[(size_t)pix * 32] = __float2half(acc[rt][ct][r] + bb);
      }
  }
}

// ---------------------------------------------------------------------------
// Kernel: out = bf16mm(accB, WoP) + bo (fp32 out)
// ---------------------------------------------------------------------------
__global__ __launch_bounds__(256, 2) void k_outproj(
    const short* __restrict__ accB, const short* __restrict__ WoP,
    const float* __restrict__ bo, float* __restrict__ out) {
  __shared__ __align__(16) char smA[16384];
  const int t = threadIdx.x, lane = t & 63, w = t >> 6;
  const int r0 = blockIdx.x * 32;
  stage_bf16(accB + (size_t)r0 * C, smA, t);
  __syncthreads();
  const int cg0 = w * 4;
  const int lr = lane & 15, lk = lane >> 4;
  GEMM_BODY(WoP)

#pragma unroll
  for (int ct = 0; ct < 4; ++ct) {
    const int col = (cg0 + ct) * 16 + lr;
    const float bb = bo[col];
#pragma unroll
    for (int rt = 0; rt < 2; ++rt)
#pragma unroll
      for (int r = 0; r < 4; ++r) {
        const int row = r0 + rt * 16 + lk * 4 + r;
        out[(size_t)row * C + col] = acc[rt][ct][r] + bb;
      }
  }
}

// ---------------------------------------------------------------------------
// Kernel: offsets/attn GEMM + softmax + 8B fixed-point descriptor build
// descD[((n*8+m)*QCHc + q)*16 + j] : uint2 {xfix|(yfix<<16), aw_half}
// fixed point: (coord + 8) * 128, coord clamped to [-8, 503]
// ---------------------------------------------------------------------------
__global__ __launch_bounds__(256, 3) void k_desc(
    const float* __restrict__ query, const float* __restrict__ refp,
    const short* __restrict__ WdP, const float* __restrict__ boff,
    const float* __restrict__ battn, uint2* __restrict__ descD, int qbase) {
  __shared__ __align__(16) char smem[50176];
  char*  smA  = smem;                       // [32][512] bf16 A-tile
  float* offs = (float*)smem;               // [32][256] (aliases smA; used later)
  float* attw = (float*)(smem + 32768);     // [32][128]
  float* refs = (float*)(smem + 49152);     // [32][8]

  const int t = threadIdx.x, lane = t & 63, w = t >> 6;
  const int n   = blockIdx.x / 340;
  const int q0c = (blockIdx.x % 340) * 32;
  const size_t qrow = (size_t)n * LEN + qbase + q0c;

  refs[t] = refp[qrow * 8 + t];
  stage_cast(query + qrow * C, smA, t);
  __syncthreads();

  f32x4 acc[2][6];
#pragma unroll
  for (int a = 0; a < 2; ++a)
#pragma unroll
    for (int b = 0; b < 6; ++b) acc[a][b] = (f32x4){0.f, 0.f, 0.f, 0.f};
  const int cgb = w * 6;
#pragma unroll
  for (int ks = 0; ks < 8; ++ks) {
    const short8v a0 = ldsA(smA, lane, 0, ks);
    const short8v a1 = ldsA(smA, lane, 1, ks);
#pragma unroll
    for (int ct = 0; ct < 6; ++ct) {
      const short8v b = ldBP(WdP, 24, cgb + ct, ks, lane);
      acc[0][ct] = MFMA(a0, b, acc[0][ct], 0, 0, 0);
      acc[1][ct] = MFMA(a1, b, acc[1][ct], 0, 0, 0);
    }
  }
  __syncthreads();   // all LDS A reads complete before aliasing writes

#pragma unroll
  for (int ct = 0; ct < 6; ++ct) {
    const int col = (cgb + ct) * 16 + (lane & 15);
    const float bb = (col < 256) ? boff[col] : battn[col - 256];
#pragma unroll
    for (int rt = 0; rt < 2; ++rt)
#pragma unroll
      for (int r = 0; r < 4; ++r) {
        const int row = rt * 16 + ((lane >> 4) << 2) + r;
        const float vv = acc[rt][ct][r] + bb;
        if (col < 256) offs[row * 256 + col] = vv;
        else           attw[row * 128 + col - 256] = vv;
      }
  }
  __syncthreads();

  // softmax over 16 per (q, m): 256 tasks
  {
    const int q = t >> 3, m = t & 7;
    float v[16], mx = -1e30f;
#pragma unroll
    for (int j = 0; j < 16; ++j) { v[j] = attw[q * 128 + m * 16 + j]; mx = fmaxf(mx, v[j]); }
    float s = 0.f;
#pragma unroll
    for (int j = 0; j < 16; ++j) { v[j] = __expf(v[j] - mx); s += v[j]; }
    const float inv = 1.f / s;
#pragma unroll
    for (int j = 0; j < 16; ++j) attw[q * 128 + m * 16 + j] = v[j] * inv;
  }
  __syncthreads();

  // descriptor build: 32 q x 128 (m,j) = 4096, 16 per thread, coalesced
#pragma unroll
  for (int i = 0; i < 16; ++i) {
    const int e = i * 256 + t;
    const int q = e >> 7, rem = e & 127;
    const int m = rem >> 4, j = rem & 15, l = j >> 2;
    const int jo = m * 16 + j;
    const float ox = offs[q * 256 + 2 * jo], oy = offs[q * 256 + 2 * jo + 1];
    const float aw = attw[q * 128 + jo];
    const float rx = refs[q * 8 + l * 2 + 0], ry = refs[q * 8 + l * 2 + 1];
    const int W = 128 >> l;
    const float x = rx * (float)W + ox - 0.5f;
    const float y = ry * (float)W + oy - 0.5f;
    const float xc = fminf(fmaxf(x, -8.f), 503.f);
    const float yc = fminf(fmaxf(y, -8.f), 503.f);
    const uint32_t xfix = (uint32_t)((xc + 8.f) * 128.f + 0.5f);
    const uint32_t yfix = (uint32_t)((yc + 8.f) * 128.f + 0.5f);
    uint2 dsc;
    dsc.x = xfix | (yfix << 16);
    dsc.y = (uint32_t)__half_as_ushort(__float2half_rn(aw));
    descD[((size_t)(n * 8 + m) * QCHc + q0c + q) * 16 + j] = dsc;
  }
}

// ---------------------------------------------------------------------------
// Kernel: gather with j-parity split. thread = (q, jh, d4); handles
// j = 2*jj + jh for jj = 0..7 (level l = jj>>1 is compile-time).
// Partial sums combined across jh via __shfl_xor(4).
// ---------------------------------------------------------------------------
__global__ __launch_bounds__(256, 4) void k_gather(
    const uint2* __restrict__ descD, const __half* __restrict__ value,
    short* __restrict__ accB, int qbase) {
  const int t = threadIdx.x;
  const int d4 = t & 3, jh = (t >> 2) & 1, ql = t >> 3;   // 32 q per block
  const int bid = blockIdx.x;
  const int s = bid & 15, qc = bid >> 4;                  // qc 0..339
  const int n = s >> 3, m = s & 7;
  const int q = qc * 32 + ql;                             // within chunk
  const uint4* dp4 = (const uint4*)(descD + ((size_t)(n * 8 + m) * QCHc + q) * 16);
  const char* vb = (const char*)value +
                   (size_t)((n * 8 + m) * LEN) * 64 + d4 * 16;

  // preload all 8 desc-uint4 (each holds j=2jj and j=2jj+1; pick half by jh)
  uint4 dd[8];
#pragma unroll
  for (int i = 0; i < 8; ++i) dd[i] = dp4[i];

  float accf[8];
#pragma unroll
  for (int i = 0; i < 8; ++i) accf[i] = 0.f;
  __half2 acch[4];
#pragma unroll
  for (int i = 0; i < 4; ++i) acch[i] = __float2half2_rn(0.f);

  union V { uint4 v; __half2 h[4]; };
  V r[2][4];
  __half2 hw[2][4];

#define DEC(JJ, SLOT)                                                         \
  {                                                                           \
    const int l_ = (JJ) >> 1;                                                 \
    const int W_ = 128 >> l_;                                                 \
    const int stl_ = (l_ == 0) ? 0 : (l_ == 1) ? 16384 : (l_ == 2) ? 20480 : 21504; \
    const uint32_t lo_ = jh ? dd[JJ].z : dd[JJ].x;                            \
    const uint32_t hi_ = jh ? dd[JJ].w : dd[JJ].y;                            \
    const int xf_ = (int)(lo_ & 0xffffu), yf_ = (int)(lo_ >> 16);             \
    const float aw_ = __half2float(__ushort_as_half((unsigned short)(hi_ & 0xffffu))); \
    const int xi_ = (xf_ >> 7) - 8, yi_ = (yf_ >> 7) - 8;                     \
    const float fx_ = (float)(xf_ & 127) * 0.0078125f;                        \
    const float fy_ = (float)(yf_ & 127) * 0.0078125f;                        \
    float wx0_ = 1.f - fx_, wx1_ = fx_, wy0_ = 1.f - fy_, wy1_ = fy_;         \
    if (xi_ < 0 || xi_ >= W_)         wx0_ = 0.f;                             \
    if (xi_ + 1 < 0 || xi_ + 1 >= W_) wx1_ = 0.f;                             \
    if (yi_ < 0 || yi_ >= W_)         wy0_ = 0.f;                             \
    if (yi_ + 1 < 0 || yi_ + 1 >= W_) wy1_ = 0.f;                             \
    const int x0_ = min(max(xi_, 0), W_ - 1), x1_ = min(max(xi_ + 1, 0), W_ - 1); \
    const int y0_ = min(max(yi_, 0), W_ - 1), y1_ = min(max(yi_ + 1, 0), W_ - 1); \
    hw[SLOT][0] = __float2half2_rn(wx0_ * wy0_ * aw_);                        \
    hw[SLOT][1] = __float2half2_rn(wx1_ * wy0_ * aw_);                        \
    hw[SLOT][2] = __float2half2_rn(wx0_ * wy1_ * aw_);                        \
    hw[SLOT][3] = __float2half2_rn(wx1_ * wy1_ * aw_);                        \
    r[SLOT][0].v = *(const uint4*)(vb + (size_t)(stl_ + y0_ * W_ + x0_) * 64u); \
    r[SLOT][1].v = *(const uint4*)(vb + (size_t)(stl_ + y0_ * W_ + x1_) * 64u); \
    r[SLOT][2].v = *(const uint4*)(vb + (size_t)(stl_ + y1_ * W_ + x0_) * 64u); \
    r[SLOT][3].v = *(const uint4*)(vb + (size_t)(stl_ + y1_ * W_ + x1_) * 64u); \
  }

#define CONSUME(SLOT)                                                         \
  {                                                                           \
    _Pragma("unroll") for (int i_ = 0; i_ < 4; ++i_) {                        \
      acch[i_] = __hfma2(r[SLOT][0].h[i_], hw[SLOT][0], acch[i_]);            \
      acch[i_] = __hfma2(r[SLOT][1].h[i_], hw[SLOT][1], acch[i_]);            \
      acch[i_] = __hfma2(r[SLOT][2].h[i_], hw[SLOT][2], acch[i_]);            \
      acch[i_] = __hfma2(r[SLOT][3].h[i_], hw[SLOT][3], acch[i_]);            \
    }                                                                         \
  }

#define PROMOTE                                                               \
  {                                                                           \
    _Pragma("unroll") for (int i_ = 0; i_ < 4; ++i_) {                        \
      const float2 f_ = __half22float2(acch[i_]);                             \
      accf[2 * i_] += f_.x; accf[2 * i_ + 1] += f_.y;                         \
      acch[i_] = __float2half2_rn(0.f);                                      \
    }                                                                         \
  }

  DEC(0, 0)
#pragma unroll
  for (int jj = 0; jj < 8; ++jj) {
    if (jj < 7) {
      if ((jj & 1) == 0) { DEC(jj + 1, 1) } else { DEC(jj + 1, 0) }
    }
    if ((jj & 1) == 0) { CONSUME(0) } else { CONSUME(1) }
    if (jj & 1) { PROMOTE }
  }
#undef DEC
#undef CONSUME
#undef PROMOTE

  // combine jh pairs (lane distance 4) and store from jh==0 lanes
#pragma unroll
  for (int i = 0; i < 8; ++i) accf[i] += __shfl_xor(accf[i], 4);
  if (jh == 0) {
    short8v o;
#pragma unroll
    for (int i = 0; i < 8; ++i) o[i] = f2bf(accf[i]);
    *(short8v*)(accB + ((size_t)n * LEN + qbase + q) * 256 + m * 32 + d4 * 8) = o;
  }
}

// ---------------------------------------------------------------------------
extern "C" void kernel_launch(void* const* d_in, const int* in_sizes, int n_in,
                              void* d_out, int out_size, void* d_ws, size_t ws_size,
                              hipStream_t stream) {
  const float* query = (const float*)d_in[0];
  const float* refp  = (const float*)d_in[1];
  const float* infl  = (const float*)d_in[2];
  const float* Woff  = (const float*)d_in[3];
  const float* boff  = (const float*)d_in[4];
  const float* Wattn = (const float*)d_in[5];
  const float* battn = (const float*)d_in[6];
  const float* Wval  = (const float*)d_in[7];
  const float* bval  = (const float*)d_in[8];
  const float* Wout  = (const float*)d_in[9];
  const float* bout  = (const float*)d_in[10];
  float* out = (float*)d_out;

  char* ws = (char*)d_ws;
  __half* value = (__half*)ws;                   // 22,282,240 B
  short*  accB  = (short*)(ws + 22282240);       // 22,282,240 B
  uint2*  desc8 = (uint2*)(ws + 44564480);       // 22,282,240 B (one chunk)
  short*  WvP   = (short*)(ws + 66846720);       // 131,072 B
  short*  WdP   = (short*)(ws + 66977792);       // 196,608 B
  short*  WoP   = (short*)(ws + 67174400);       // 131,072 B  (total 67.3 MB)

  k_wpack<<<dim3(384, 3), 256, 0, stream>>>(Wval, Woff, Wattn, Wout,
                                            WvP, WdP, WoP);

  k_valproj<<<(NB * LEN) / 32, 256, 0, stream>>>(infl, WvP, bval, value);

  for (int c = 0; c < 2; ++c) {
    k_desc<<<NB * (QCHc / 32), 256, 0, stream>>>(query, refp, WdP, boff, battn,
                                                 desc8, c * QCHc);
    k_gather<<<16 * (QCHc / 32), 256, 0, stream>>>(desc8, value, accB, c * QCHc);
  }

  k_outproj<<<(NB * LEN) / 32, 256, 0, stream>>>(accB, WoP, bout, out);
}

// Round 16
// 153.200 us; speedup vs baseline: 1.3934x; 1.3934x over previous
//
#include <hip/hip_runtime.h>
#include <hip/hip_fp16.h>
#include <math.h>
#include <stdint.h>

// MSDeformAttn. N=2, C=256, M=8, L=4, P=4, D=32, LEN=21760
// R16: R12 state; gather rebuilt as 4 level-groups x 16 loads with
//      sched_barrier(0) fences to force a real 16-deep load pipeline.

constexpr int NB  = 2;
constexpr int C   = 256;
constexpr int M   = 8;
constexpr int D   = 32;
constexpr int LEN = 21760;
constexpr int QCHc = LEN / 2;   // 10880 queries per chunk (per batch)

typedef __attribute__((ext_vector_type(8))) short short8v;
typedef __attribute__((ext_vector_type(4))) float f32x4;

__device__ __forceinline__ short f2bf(float x) {
  uint32_t u = __float_as_uint(x);
  u = (u + 0x7fffu + ((u >> 16) & 1u)) >> 16;
  return (short)u;
}

// ---------------------------------------------------------------------------
// Weight prepack into per-fragment-coalesced layout:
// WP[((ks*NCG+cg)*64 + lane)*8 + e] = W[ks*32 + (lane>>4)*8 + e][cg*16 + (lane&15)]
// ---------------------------------------------------------------------------
__global__ __launch_bounds__(256) void k_wpack(
    const float* __restrict__ Wval, const float* __restrict__ Woff,
    const float* __restrict__ Wattn, const float* __restrict__ Wout,
    short* __restrict__ WvP, short* __restrict__ WdP, short* __restrict__ WoP) {
  const int job = blockIdx.y;
  const int ncols = (job == 1) ? 384 : 256;
  const int NCG = ncols / 16;
  const int elems = 256 * ncols;
  const int idx = blockIdx.x * 256 + threadIdx.x;
  if (idx >= elems) return;
  const int e    = idx & 7;
  const int lane = (idx >> 3) & 63;
  const int lr = lane & 15, lk = lane >> 4;
  const int cgks = idx >> 9;
  const int cg = cgks % NCG, ks = cgks / NCG;
  const int k = ks * 32 + lk * 8 + e;
  const int col = cg * 16 + lr;
  float v;
  if (job == 0)      v = Wval[(size_t)k * 256 + col];
  else if (job == 2) v = Wout[(size_t)k * 256 + col];
  else               v = (col < 256) ? Woff[(size_t)k * 256 + col]
                                     : Wattn[(size_t)k * 128 + col - 256];
  short* dst = (job == 0) ? WvP : (job == 1) ? WdP : WoP;
  dst[idx] = f2bf(v);
}

__device__ __forceinline__ short8v ldBP(const short* __restrict__ WP, int NCG,
                                        int cg, int ks, int lane) {
  const int4 v = *(const int4*)(WP + ((size_t)((ks * NCG + cg) * 64 + lane)) * 8);
  union { int4 i; short8v s; } u; u.i = v; return u.s;
}

// ---------------------------------------------------------------------------
// LDS staging (32 rows x 256 k, bf16, XOR-swizzled) + A fragment loads
// ---------------------------------------------------------------------------
__device__ __forceinline__ void stage_cast(const float* __restrict__ p, char* sm, int t) {
  const int r = t >> 3, seg = t & 7;
  const float4* s = (const float4*)(p + (size_t)r * C + seg * 32);
  short v[32];
#pragma unroll
  for (int i = 0; i < 8; ++i) {
    float4 f = s[i];
    v[i * 4 + 0] = f2bf(f.x); v[i * 4 + 1] = f2bf(f.y);
    v[i * 4 + 2] = f2bf(f.z); v[i * 4 + 3] = f2bf(f.w);
  }
#pragma unroll
  for (int i = 0; i < 4; ++i) {
    const int kb = (seg * 32 + i * 8) * 2;
    *(int4*)(sm + r * 512 + (kb ^ ((r & 7) << 4))) = ((const int4*)v)[i];
  }
}

__device__ __forceinline__ void stage_bf16(const short* __restrict__ p, char* sm, int t) {
  const int r = t >> 3, seg = t & 7;
  const int4* s = (const int4*)(p + (size_t)r * C + seg * 32);
#pragma unroll
  for (int i = 0; i < 4; ++i) {
    const int kb = (seg * 32 + i * 8) * 2;
    *(int4*)(sm + r * 512 + (kb ^ ((r & 7) << 4))) = s[i];
  }
}

__device__ __forceinline__ short8v ldsA(const char* sm, int lane, int rt, int ks) {
  const int row = rt * 16 + (lane & 15);
  const int kb  = ks * 64 + ((lane >> 4) << 4);
  const int4 v = *(const int4*)(sm + row * 512 + (kb ^ ((row & 7) << 4)));
  union { int4 i; short8v s; } u; u.i = v; return u.s;
}

#define MFMA __builtin_amdgcn_mfma_f32_16x16x32_bf16

// ---------------------------------------------------------------------------
// GEMM body shared by valproj/outproj (proven in R10)
// ---------------------------------------------------------------------------
#define GEMM_BODY(WP)                                                       \
  short8v a[2][8];                                                          \
  _Pragma("unroll") for (int rt = 0; rt < 2; ++rt)                          \
  _Pragma("unroll") for (int ks = 0; ks < 8; ++ks)                          \
      a[rt][ks] = ldsA(smA, lane, rt, ks);                                  \
  f32x4 acc[2][4];                                                          \
  _Pragma("unroll") for (int rt = 0; rt < 2; ++rt)                          \
  _Pragma("unroll") for (int ct = 0; ct < 4; ++ct)                          \
      acc[rt][ct] = (f32x4){0.f, 0.f, 0.f, 0.f};                            \
  short8v b0[8], b1[8];                                                     \
  _Pragma("unroll") for (int ks = 0; ks < 8; ++ks)                          \
      b0[ks] = ldBP(WP, 16, cg0 + 0, ks, lane);                             \
  _Pragma("unroll") for (int ks = 0; ks < 8; ++ks)                          \
      b1[ks] = ldBP(WP, 16, cg0 + 1, ks, lane);                             \
  _Pragma("unroll") for (int ks = 0; ks < 8; ++ks) {                        \
    acc[0][0] = MFMA(a[0][ks], b0[ks], acc[0][0], 0, 0, 0);                 \
    acc[1][0] = MFMA(a[1][ks], b0[ks], acc[1][0], 0, 0, 0);                 \
  }                                                                         \
  _Pragma("unroll") for (int ks = 0; ks < 8; ++ks)                          \
      b0[ks] = ldBP(WP, 16, cg0 + 2, ks, lane);                             \
  _Pragma("unroll") for (int ks = 0; ks < 8; ++ks) {                        \
    acc[0][1] = MFMA(a[0][ks], b1[ks], acc[0][1], 0, 0, 0);                 \
    acc[1][1] = MFMA(a[1][ks], b1[ks], acc[1][1], 0, 0, 0);                 \
  }                                                                         \
  _Pragma("unroll") for (int ks = 0; ks < 8; ++ks)                          \
      b1[ks] = ldBP(WP, 16, cg0 + 3, ks, lane);                             \
  _Pragma("unroll") for (int ks = 0; ks < 8; ++ks) {                        \
    acc[0][2] = MFMA(a[0][ks], b0[ks], acc[0][2], 0, 0, 0);                 \
    acc[1][2] = MFMA(a[1][ks], b0[ks], acc[1][2], 0, 0, 0);                 \
  }                                                                         \
  _Pragma("unroll") for (int ks = 0; ks < 8; ++ks) {                        \
    acc[0][3] = MFMA(a[0][ks], b1[ks], acc[0][3], 0, 0, 0);                 \
    acc[1][3] = MFMA(a[1][ks], b1[ks], acc[1][3], 0, 0, 0);                 \
  }

// ---------------------------------------------------------------------------
// Kernel: value = bf16mm(input_flatten, WvP) + bv -> fp16 value[n][m][pix][d]
// ---------------------------------------------------------------------------
__global__ __launch_bounds__(256, 2) void k_valproj(
    const float* __restrict__ infl, const short* __restrict__ WvP,
    const float* __restrict__ bv, __half* __restrict__ value) {
  __shared__ __align__(16) char smA[16384];
  const int t = threadIdx.x, lane = t & 63, w = t >> 6;
  const int r0 = blockIdx.x * 32;
  stage_cast(infl + (size_t)r0 * C, smA, t);
  __syncthreads();
  const int cg0 = w * 4;
  const int lr = lane & 15, lk = lane >> 4;
  GEMM_BODY(WvP)

  const int n = (blockIdx.x >= (LEN / 32)) ? 1 : 0;
  const int pixbase = r0 - n * LEN;
#pragma unroll
  for (int ct = 0; ct < 4; ++ct) {
    const int col = (cg0 + ct) * 16 + lr;
    const float bb = bv[col];
    const int m = col >> 5, d = col & 31;
    __half* vp = value + ((size_t)(n * 8 + m) * LEN) * 32 + d;
#pragma unroll
    for (int rt = 0; rt < 2; ++rt)
#pragma unroll
      for (int r = 0; r < 4; ++r) {
        const int pix = pixbase + rt * 16 + lk * 4 + r;
        vp[(size_t)pix * 32] = __float2half(acc[rt][ct][r] + bb);
      }
  }
}

// ---------------------------------------------------------------------------
// Kernel: out = bf16mm(accB, WoP) + bo (fp32 out)
// ---------------------------------------------------------------------------
__global__ __launch_bounds__(256, 2) void k_outproj(
    const short* __restrict__ accB, const short* __restrict__ WoP,
    const float* __restrict__ bo, float* __restrict__ out) {
  __shared__ __align__(16) char smA[16384];
  const int t = threadIdx.x, lane = t & 63, w = t >> 6;
  const int r0 = blockIdx.x * 32;
  stage_bf16(accB + (size_t)r0 * C, smA, t);
  __syncthreads();
  const int cg0 = w * 4;
  const int lr = lane & 15, lk = lane >> 4;
  GEMM_BODY(WoP)

#pragma unroll
  for (int ct = 0; ct < 4; ++ct) {
    const int col = (cg0 + ct) * 16 + lr;
    const float bb = bo[col];
#pragma unroll
    for (int rt = 0; rt < 2; ++rt)
#pragma unroll
      for (int r = 0; r < 4; ++r) {
        const int row = r0 + rt * 16 + lk * 4 + r;
        out[(size_t)row * C + col] = acc[rt][ct][r] + bb;
      }
  }
}

// ---------------------------------------------------------------------------
// Kernel: offsets/attn GEMM + softmax + 8B fixed-point descriptor build
// descD[((n*8+m)*QCHc + q)*16 + j] : uint2 {xfix|(yfix<<16), aw_half}
// fixed point: (coord + 8) * 128, coord clamped to [-8, 503]
// ---------------------------------------------------------------------------
__global__ __launch_bounds__(256, 3) void k_desc(
    const float* __restrict__ query, const float* __restrict__ refp,
    const short* __restrict__ WdP, const float* __restrict__ boff,
    const float* __restrict__ battn, uint2* __restrict__ descD, int qbase) {
  __shared__ __align__(16) char smem[50176];
  char*  smA  = smem;                       // [32][512] bf16 A-tile
  float* offs = (float*)smem;               // [32][256] (aliases smA; used later)
  float* attw = (float*)(smem + 32768);     // [32][128]
  float* refs = (float*)(smem + 49152);     // [32][8]

  const int t = threadIdx.x, lane = t & 63, w = t >> 6;
  const int n   = blockIdx.x / 340;
  const int q0c = (blockIdx.x % 340) * 32;
  const size_t qrow = (size_t)n * LEN + qbase + q0c;

  refs[t] = refp[qrow * 8 + t];
  stage_cast(query + qrow * C, smA, t);
  __syncthreads();

  f32x4 acc[2][6];
#pragma unroll
  for (int a = 0; a < 2; ++a)
#pragma unroll
    for (int b = 0; b < 6; ++b) acc[a][b] = (f32x4){0.f, 0.f, 0.f, 0.f};
  const int cgb = w * 6;
#pragma unroll
  for (int ks = 0; ks < 8; ++ks) {
    const short8v a0 = ldsA(smA, lane, 0, ks);
    const short8v a1 = ldsA(smA, lane, 1, ks);
#pragma unroll
    for (int ct = 0; ct < 6; ++ct) {
      const short8v b = ldBP(WdP, 24, cgb + ct, ks, lane);
      acc[0][ct] = MFMA(a0, b, acc[0][ct], 0, 0, 0);
      acc[1][ct] = MFMA(a1, b, acc[1][ct], 0, 0, 0);
    }
  }
  __syncthreads();   // all LDS A reads complete before aliasing writes

#pragma unroll
  for (int ct = 0; ct < 6; ++ct) {
    const int col = (cgb + ct) * 16 + (lane & 15);
    const float bb = (col < 256) ? boff[col] : battn[col - 256];
#pragma unroll
    for (int rt = 0; rt < 2; ++rt)
#pragma unroll
      for (int r = 0; r < 4; ++r) {
        const int row = rt * 16 + ((lane >> 4) << 2) + r;
        const float vv = acc[rt][ct][r] + bb;
        if (col < 256) offs[row * 256 + col] = vv;
        else           attw[row * 128 + col - 256] = vv;
      }
  }
  __syncthreads();

  // softmax over 16 per (q, m): 256 tasks
  {
    const int q = t >> 3, m = t & 7;
    float v[16], mx = -1e30f;
#pragma unroll
    for (int j = 0; j < 16; ++j) { v[j] = attw[q * 128 + m * 16 + j]; mx = fmaxf(mx, v[j]); }
    float s = 0.f;
#pragma unroll
    for (int j = 0; j < 16; ++j) { v[j] = __expf(v[j] - mx); s += v[j]; }
    const float inv = 1.f / s;
#pragma unroll
    for (int j = 0; j < 16; ++j) attw[q * 128 + m * 16 + j] = v[j] * inv;
  }
  __syncthreads();

  // descriptor build: 32 q x 128 (m,j) = 4096, 16 per thread, coalesced
#pragma unroll
  for (int i = 0; i < 16; ++i) {
    const int e = i * 256 + t;
    const int q = e >> 7, rem = e & 127;
    const int m = rem >> 4, j = rem & 15, l = j >> 2;
    const int jo = m * 16 + j;
    const float ox = offs[q * 256 + 2 * jo], oy = offs[q * 256 + 2 * jo + 1];
    const float aw = attw[q * 128 + jo];
    const float rx = refs[q * 8 + l * 2 + 0], ry = refs[q * 8 + l * 2 + 1];
    const int W = 128 >> l;
    const float x = rx * (float)W + ox - 0.5f;
    const float y = ry * (float)W + oy - 0.5f;
    const float xc = fminf(fmaxf(x, -8.f), 503.f);
    const float yc = fminf(fmaxf(y, -8.f), 503.f);
    const uint32_t xfix = (uint32_t)((xc + 8.f) * 128.f + 0.5f);
    const uint32_t yfix = (uint32_t)((yc + 8.f) * 128.f + 0.5f);
    uint2 dsc;
    dsc.x = xfix | (yfix << 16);
    dsc.y = (uint32_t)__half_as_ushort(__float2half_rn(aw));
    descD[((size_t)(n * 8 + m) * QCHc + q0c + q) * 16 + j] = dsc;
  }
}

// ---------------------------------------------------------------------------
// Kernel: gather with sched_barrier-fenced 16-deep load groups.
// Group g covers j = 4g..4g+3 (one level): decode+issue 16 loads, fence,
// then consume. R12 thread mapping and store (full-wave, coalesced).
// ---------------------------------------------------------------------------
__global__ __launch_bounds__(256, 3) void k_gather(
    const uint2* __restrict__ descD, const __half* __restrict__ value,
    short* __restrict__ accB, int qbase) {
  const int t = threadIdx.x;
  const int d4 = t & 3, ql = t >> 2;          // 64 queries per block
  const int bid = blockIdx.x;
  const int s = bid & 15, qc = bid >> 4;      // slice, query-chunk (170)
  const int n = s >> 3, m = s & 7;
  const int q = qc * 64 + ql;                 // within chunk
  const uint4* dp4 = (const uint4*)(descD + ((size_t)(n * 8 + m) * QCHc + q) * 16);
  const char* vb = (const char*)value +
                   (size_t)((n * 8 + m) * LEN) * 64 + d4 * 16;

  // preload all 16 descriptors (contiguous 128 B); fence keeps them resident
  uint4 dd[8];
#pragma unroll
  for (int i = 0; i < 8; ++i) dd[i] = dp4[i];
  __builtin_amdgcn_sched_barrier(0);

  float accf[8];
#pragma unroll
  for (int i = 0; i < 8; ++i) accf[i] = 0.f;

  union V { uint4 v; __half2 h[4]; };
  V r0_, r1_, r2_, r3_, r4_, r5_, r6_, r7_;
  V r8_, r9_, rA_, rB_, rC_, rD_, rE_, rF_;
  __half2 hw[4][4];

#define DECJ(J, KK, RA, RB, RC, RD)                                           \
  {                                                                           \
    constexpr int l_ = (J) >> 2;                                              \
    constexpr int W_ = 128 >> l_;                                             \
    constexpr int stl_ = (l_ == 0) ? 0 : (l_ == 1) ? 16384 : (l_ == 2) ? 20480 : 21504; \
    const uint32_t lo_ = ((J) & 1) ? dd[(J) >> 1].z : dd[(J) >> 1].x;         \
    const uint32_t hi_ = ((J) & 1) ? dd[(J) >> 1].w : dd[(J) >> 1].y;         \
    const int xf_ = (int)(lo_ & 0xffffu), yf_ = (int)(lo_ >> 16);             \
    const float aw_ = __half2float(__ushort_as_half((unsigned short)(hi_ & 0xffffu))); \
    const int xi_ = (xf_ >> 7) - 8, yi_ = (yf_ >> 7) - 8;                     \
    const float fx_ = (float)(xf_ & 127) * 0.0078125f;                        \
    const float fy_ = (float)(yf_ & 127) * 0.0078125f;                        \
    float wx0_ = 1.f - fx_, wx1_ = fx_, wy0_ = 1.f - fy_, wy1_ = fy_;         \
    if (xi_ < 0 || xi_ >= W_)         wx0_ = 0.f;                             \
    if (xi_ + 1 < 0 || xi_ + 1 >= W_) wx1_ = 0.f;                             \
    if (yi_ < 0 || yi_ >= W_)         wy0_ = 0.f;                             \
    if (yi_ + 1 < 0 || yi_ + 1 >= W_) wy1_ = 0.f;                             \
    const int x0_ = min(max(xi_, 0), W_ - 1), x1_ = min(max(xi_ + 1, 0), W_ - 1); \
    const int y0_ = min(max(yi_, 0), W_ - 1), y1_ = min(max(yi_ + 1, 0), W_ - 1); \
    hw[KK][0] = __float2half2_rn(wx0_ * wy0_ * aw_);                          \
    hw[KK][1] = __float2half2_rn(wx1_ * wy0_ * aw_);                          \
    hw[KK][2] = __float2half2_rn(wx0_ * wy1_ * aw_);                          \
    hw[KK][3] = __float2half2_rn(wx1_ * wy1_ * aw_);                          \
    RA.v = *(const uint4*)(vb + (size_t)(stl_ + y0_ * W_ + x0_) * 64u);       \
    RB.v = *(const uint4*)(vb + (size_t)(stl_ + y0_ * W_ + x1_) * 64u);       \
    RC.v = *(const uint4*)(vb + (size_t)(stl_ + y1_ * W_ + x0_) * 64u);       \
    RD.v = *(const uint4*)(vb + (size_t)(stl_ + y1_ * W_ + x1_) * 64u);       \
  }

#define CONSJ(KK, RA, RB, RC, RD, ACH)                                        \
  {                                                                           \
    _Pragma("unroll") for (int i_ = 0; i_ < 4; ++i_) {                        \
      ACH[i_] = __hfma2(RA.h[i_], hw[KK][0], ACH[i_]);                        \
      ACH[i_] = __hfma2(RB.h[i_], hw[KK][1], ACH[i_]);                        \
      ACH[i_] = __hfma2(RC.h[i_], hw[KK][2], ACH[i_]);                        \
      ACH[i_] = __hfma2(RD.h[i_], hw[KK][3], ACH[i_]);                        \
    }                                                                         \
  }

#define PROM(ACH)                                                             \
  {                                                                           \
    _Pragma("unroll") for (int i_ = 0; i_ < 4; ++i_) {                        \
      const float2 f_ = __half22float2(ACH[i_]);                              \
      accf[2 * i_] += f_.x; accf[2 * i_ + 1] += f_.y;                         \
      ACH[i_] = __float2half2_rn(0.f);                                        \
    }                                                                         \
  }

#define GROUP(G)                                                              \
  {                                                                           \
    DECJ(4 * (G) + 0, 0, r0_, r1_, r2_, r3_)                                  \
    DECJ(4 * (G) + 1, 1, r4_, r5_, r6_, r7_)                                  \
    DECJ(4 * (G) + 2, 2, r8_, r9_, rA_, rB_)                                  \
    DECJ(4 * (G) + 3, 3, rC_, rD_, rE_, rF_)                                  \
    __builtin_amdgcn_sched_barrier(0);                                        \
    __half2 acch[4];                                                          \
    _Pragma("unroll") for (int i_ = 0; i_ < 4; ++i_)                          \
        acch[i_] = __float2half2_rn(0.f);                                     \
    CONSJ(0, r0_, r1_, r2_, r3_, acch)                                        \
    CONSJ(1, r4_, r5_, r6_, r7_, acch)                                        \
    PROM(acch)                                                                \
    CONSJ(2, r8_, r9_, rA_, rB_, acch)                                        \
    CONSJ(3, rC_, rD_, rE_, rF_, acch)                                        \
    PROM(acch)                                                                \
  }

  GROUP(0)
  GROUP(1)
  GROUP(2)
  GROUP(3)
#undef DECJ
#undef CONSJ
#undef PROM
#undef GROUP

  short8v o;
#pragma unroll
  for (int i = 0; i < 8; ++i) o[i] = f2bf(accf[i]);
  *(short8v*)(accB + ((size_t)n * LEN + qbase + q) * 256 + m * 32 + d4 * 8) = o;
}

// ---------------------------------------------------------------------------
extern "C" void kernel_launch(void* const* d_in, const int* in_sizes, int n_in,
                              void* d_out, int out_size, void* d_ws, size_t ws_size,
                              hipStream_t stream) {
  const float* query = (const float*)d_in[0];
  const float* refp  = (const float*)d_in[1];
  const float* infl  = (const float*)d_in[2];
  const float* Woff  = (const float*)d_in[3];
  const float* boff  = (const float*)d_in[4];
  const float* Wattn = (const float*)d_in[5];
  const float* battn = (const float*)d_in[6];
  const float* Wval  = (const float*)d_in[7];
  const float* bval  = (const float*)d_in[8];
  const float* Wout  = (const float*)d_in[9];
  const float* bout  = (const float*)d_in[10];
  float* out = (float*)d_out;

  char* ws = (char*)d_ws;
  __half* value = (__half*)ws;                   // 22,282,240 B
  short*  accB  = (short*)(ws + 22282240);       // 22,282,240 B
  uint2*  desc8 = (uint2*)(ws + 44564480);       // 22,282,240 B (one chunk)
  short*  WvP   = (short*)(ws + 66846720);       // 131,072 B
  short*  WdP   = (short*)(ws + 66977792);       // 196,608 B
  short*  WoP   = (short*)(ws + 67174400);       // 131,072 B  (total 67.3 MB)

  k_wpack<<<dim3(384, 3), 256, 0, stream>>>(Wval, Woff, Wattn, Wout,
                                            WvP, WdP, WoP);

  k_valproj<<<(NB * LEN) / 32, 256, 0, stream>>>(infl, WvP, bval, value);

  for (int c = 0; c < 2; ++c) {
    k_desc<<<NB * (QCHc / 32), 256, 0, stream>>>(query, refp, WdP, boff, battn,
                                                 desc8, c * QCHc);
    k_gather<<<16 * (QCHc / 64), 256, 0, stream>>>(desc8, value, accB, c * QCHc);
  }

  k_outproj<<<(NB * LEN) / 32, 256, 0, stream>>>(accB, WoP, bout, out);
}